// Round 10
// baseline (150.280 us; speedup 1.0000x reference)
//
#include <hip/hip_runtime.h>

#define N_NODES  50000
#define N_EDGES  600000
#define CHANNELS 128
#define HEADS    8
#define HEAD_DIM 16   // CHANNELS / HEADS
#define NSHARD   4    // cursor shards per node (contention 12 -> ~3 per address)
#define CAP_S    16   // bucket capacity per shard; shard load ~ Poisson(3)
#define CAP      (NSHARD * CAP_S)   // 64 slots per node

#define PREP_BLOCK 256
#define EPT        2                                   // edges per thread (scatter)
#define SCAT_TH    (N_EDGES / EPT)                     // 300000 scatter threads
#define SCAT_VB    ((SCAT_TH + PREP_BLOCK - 1) / PREP_BLOCK)          // 1172
#define LOGIT_VB   ((N_NODES * (CHANNELS / 4)) / PREP_BLOCK)          // 6250
#define WPB        4    // waves (nodes) per block in the fused kernel

// cursor layout: shard counter at cursor[(n*NSHARD + s)*16]  (one 64B line each)

// ---------------------------------------------------------------------------
// K1 (fused prep):
//  blocks [0, SCAT_VB): scatter src ids (ushort) into per-dst sharded buckets.
//    Shard = (edge ordinal)&3 -> same-address RMW serialization drops ~4x.
//  blocks [SCAT_VB, ...): per-node logit halves + bf16(x), float4/thread.
// ---------------------------------------------------------------------------
__global__ void prep_kernel(const float* __restrict__ x,
                            const float* __restrict__ att,
                            const int*   __restrict__ src,
                            const int*   __restrict__ dst,
                            int*            __restrict__ cursor,
                            unsigned short* __restrict__ bucket,
                            float*          __restrict__ ls8,
                            float*          __restrict__ ld8,
                            unsigned short* __restrict__ xb) {
    int b = blockIdx.x;
    if (b < SCAT_VB) {
        int t = b * PREP_BLOCK + threadIdx.x;
        if (t < SCAT_TH) {
            int dd[EPT], ss[EPT], pp[EPT];
#pragma unroll
            for (int k = 0; k < EPT; ++k) {
                int e = t + k * SCAT_TH;            // coalesced per k
                dd[k] = dst[e];
                ss[k] = src[e];
            }
#pragma unroll
            for (int k = 0; k < EPT; ++k) {
                int sh = (t + k) & (NSHARD - 1);
                pp[k] = atomicAdd(&cursor[(dd[k] * NSHARD + sh) * 16], 1);
            }
#pragma unroll
            for (int k = 0; k < EPT; ++k) {
                int sh = (t + k) & (NSHARD - 1);
                if (pp[k] < CAP_S)
                    bucket[(size_t)dd[k] * CAP + sh * CAP_S + pp[k]] =
                        (unsigned short)ss[k];
            }
        }
    } else {
        int gid = (b - SCAT_VB) * PREP_BLOCK + threadIdx.x;  // (node, float4-slot)
        int n  = gid >> 5;          // 32 float4s per node
        int c4 = gid & 31;
        int h  = c4 >> 2;           // 4 float4s per head
        int j4 = c4 & 3;

        float4 v = ((const float4*)x)[gid];

        // bf16 round-to-nearest-even, packed store (8B)
        unsigned int ux = __float_as_uint(v.x), uy = __float_as_uint(v.y);
        unsigned int uz = __float_as_uint(v.z), uw = __float_as_uint(v.w);
        ushort4 pk;
        pk.x = (unsigned short)((ux + 0x7FFFu + ((ux >> 16) & 1u)) >> 16);
        pk.y = (unsigned short)((uy + 0x7FFFu + ((uy >> 16) & 1u)) >> 16);
        pk.z = (unsigned short)((uz + 0x7FFFu + ((uz >> 16) & 1u)) >> 16);
        pk.w = (unsigned short)((uw + 0x7FFFu + ((uw >> 16) & 1u)) >> 16);
        ((ushort4*)xb)[gid] = pk;

        // att row = 32 floats = 8 float4s: [a_src(4), a_dst(4)]
        float4 as4 = ((const float4*)att)[h * 8 + j4];
        float4 ad4 = ((const float4*)att)[h * 8 + 4 + j4];
        float ts = v.x * as4.x + v.y * as4.y + v.z * as4.z + v.w * as4.w;
        float td = v.x * ad4.x + v.y * ad4.y + v.z * ad4.z + v.w * ad4.w;
        ts += __shfl_xor(ts, 1, 4); ts += __shfl_xor(ts, 2, 4);
        td += __shfl_xor(td, 1, 4); td += __shfl_xor(td, 2, 4);
        if (j4 == 0) {
            ls8[n * HEADS + h] = ts;
            ld8[n * HEADS + h] = td;
        }
    }
}

// ---------------------------------------------------------------------------
// K2: fused GAT aggregation.  One 64-lane wave per node.
// Bucket is 4 shard-runs of 16; a ~6-op remap densifies lane->slot so the
// rest of the kernel sees a contiguous edge list.
// Pass 1 (h=lane>>3, j=lane&7): logits in registers, 8-lane shuffle max
//   (clamped at 0 == reference's max(seg_max,0)), one exp per (edge,head)
//   -> LDS, denominator reduced in-register.
// Pass 2 (r=lane>>5, l32=lane&31): two edges per wave-load (ushort4/lane,
//   half-wave = one 256B row), window 8 slots = 16 edges in flight.
// ---------------------------------------------------------------------------
__global__ void fused_gat_kernel(const unsigned short* __restrict__ xb,
                                 const float* __restrict__ ls8,
                                 const float* __restrict__ ld8,
                                 const int*   __restrict__ cursor,
                                 const unsigned short* __restrict__ bucket,
                                 float*       __restrict__ out) {
    __shared__ float s_p[WPB * CAP * HEADS];     // 8 KB: staged softmax numerators

    int wave = threadIdx.x >> 6;                 // 0..WPB-1
    int lane = threadIdx.x & 63;
    int n = blockIdx.x * WPB + wave;
    if (n >= N_NODES) return;
    int h = lane >> 3;                           // pass-1 head
    int j = lane & 7;
    int r   = lane >> 5;                         // pass-2: which edge of pair
    int l32 = lane & 31;                         // pass-2: channel quad
    int h2  = l32 >> 2;                          // pass-2 head

    // shard counts -> dense lane->slot remap
    int csh = 0;
    if (lane < NSHARD) csh = cursor[(n * NSHARD + lane) * 16];
    int c0 = __shfl(csh, 0), c1 = __shfl(csh, 1);
    int c2 = __shfl(csh, 2), c3 = __shfl(csh, 3);
    c0 = min(c0, CAP_S); c1 = min(c1, CAP_S);
    c2 = min(c2, CAP_S); c3 = min(c3, CAP_S);
    int b1 = c0, b2 = c0 + c1, b3 = c0 + c1 + c2;
    int cnt = b3 + c3;

    int i0 = lane;
    int slot = (i0 < b1) ? i0
             : (i0 < b2) ? CAP_S + (i0 - b1)
             : (i0 < b3) ? 2 * CAP_S + (i0 - b2)
                         : 3 * CAP_S + (i0 - b3);
    slot = min(slot, CAP - 1);
    int   myidx = (int)bucket[(size_t)n * CAP + slot];
    float ldst  = ld8[n * HEADS + h];

    float* sp = s_p + wave * (CAP * HEADS);

    // ---- pass 1: logits in registers, per-head max, single exp per value ----
    float av[8];
    float mymax = -1e30f;
#pragma unroll
    for (int k = 0; k < 8; ++k) {
        int i = j + 8 * k;
        av[k] = -1e30f;
        if (i < cnt) {
            int   s  = __shfl(myidx, i);
            float lg = ls8[s * HEADS + h] + ldst;
            float a  = (lg >= 0.0f) ? lg : 0.2f * lg;   // LeakyReLU(0.2)
            av[k] = a;
            mymax = fmaxf(mymax, a);
        }
    }
#pragma unroll
    for (int o = 4; o >= 1; o >>= 1) mymax = fmaxf(mymax, __shfl_xor(mymax, o, 8));
    float m = fmaxf(mymax, 0.0f);                // reference clamps seg_max at 0

    float myl = 0.0f;
#pragma unroll
    for (int k = 0; k < 8; ++k) {
        int i = j + 8 * k;
        if (i < cnt) {
            float p = __expf(av[k] - m);
            sp[i * HEADS + h] = p;               // 2-way bank aliasing only
            myl += p;
        }
    }
#pragma unroll
    for (int o = 4; o >= 1; o >>= 1) myl += __shfl_xor(myl, o, 8);

    // ---- pass 2: weighted accumulate, 2 edges/load, window 8 slots ----
#define LP(k) ( ((const uint2*)(xb + (size_t)__shfl(myidx, ((2*(k)+r) < cnt) ? (2*(k)+r) : 0) * CHANNELS))[l32] )
    uint2 q[8];
#pragma unroll
    for (int k = 0; k < 8; ++k) q[k] = LP(k);

    float a0 = 0.f, a1 = 0.f, a2 = 0.f, a3 = 0.f;
    int npair = (cnt + 1) >> 1;
    int k = 0;
    for (; k + 4 <= npair; k += 4) {
#pragma unroll
        for (int u = 0; u < 4; ++u) {
            int e2 = 2 * (k + u) + r;
            float p = (e2 < cnt) ? sp[e2 * HEADS + h2] : 0.0f;
            uint2 qq = q[u];
            a0 += p * __uint_as_float(qq.x << 16);
            a1 += p * __uint_as_float(qq.x & 0xFFFF0000u);
            a2 += p * __uint_as_float(qq.y << 16);
            a3 += p * __uint_as_float(qq.y & 0xFFFF0000u);
        }
#pragma unroll
        for (int u = 0; u < 4; ++u) q[u] = q[u + 4];
#pragma unroll
        for (int u = 0; u < 4; ++u) q[u + 4] = LP(k + 8 + u);
    }
    for (; k < npair; ++k) {                     // tail 0..3 pairs
        int e2 = 2 * k + r;
        float p = (e2 < cnt) ? sp[e2 * HEADS + h2] : 0.0f;
        uint2 qq = q[0];
        a0 += p * __uint_as_float(qq.x << 16);
        a1 += p * __uint_as_float(qq.x & 0xFFFF0000u);
        a2 += p * __uint_as_float(qq.y << 16);
        a3 += p * __uint_as_float(qq.y & 0xFFFF0000u);
#pragma unroll
        for (int u = 0; u < 7; ++u) q[u] = q[u + 1];
    }
#undef LP

    // merge even/odd-edge halves
    a0 += __shfl_xor(a0, 32);
    a1 += __shfl_xor(a1, 32);
    a2 += __shfl_xor(a2, 32);
    a3 += __shfl_xor(a3, 32);

    // denominator for pass-2 head layout: lane h2*8 holds head h2's sum
    float denom = __shfl(myl, h2 * 8);
    float inv = 1.0f / fmaxf(denom, 1e-10f);

    if (lane < 32) {
        float4 o4 = make_float4(a0 * inv, a1 * inv, a2 * inv, a3 * inv);
        ((float4*)(out + (size_t)n * CHANNELS))[l32] = o4;
    }
}

// ---------------------------------------------------------------------------
extern "C" void kernel_launch(void* const* d_in, const int* in_sizes, int n_in,
                              void* d_out, int out_size, void* d_ws, size_t ws_size,
                              hipStream_t stream) {
    const float* x   = (const float*)d_in[0];
    const int*   ei  = (const int*)  d_in[1];   // (2, N_EDGES) row-major
    const float* att = (const float*)d_in[2];
    const int* src = ei;
    const int* dst = ei + N_EDGES;
    float* out = (float*)d_out;

    // Workspace layout:
    //   cursor : N_NODES * NSHARD * 16 ints  (12.8 MB, one line per shard)
    //   bucket : N_NODES * CAP ushorts       ( 6.4 MB)
    //   ls8    : N_NODES * HEADS floats      ( 1.6 MB)
    //   ld8    : N_NODES * HEADS floats      ( 1.6 MB)
    //   xb     : N_NODES * CHANNELS ushorts  (12.8 MB)
    int*            cursor = (int*)d_ws;
    unsigned short* bucket = (unsigned short*)(cursor + (size_t)N_NODES * NSHARD * 16);
    float*          ls8    = (float*)(bucket + (size_t)N_NODES * CAP);
    float*          ld8    = ls8 + (size_t)N_NODES * HEADS;
    unsigned short* xb     = (unsigned short*)(ld8 + (size_t)N_NODES * HEADS);

    hipMemsetAsync(cursor, 0, sizeof(int) * (size_t)N_NODES * NSHARD * 16, stream);

    prep_kernel<<<SCAT_VB + LOGIT_VB, PREP_BLOCK, 0, stream>>>(
        x, att, src, dst, cursor, bucket, ls8, ld8, xb);

    {
        int grid = (N_NODES + WPB - 1) / WPB;
        fused_gat_kernel<<<grid, 64 * WPB, 0, stream>>>(
            xb, ls8, ld8, cursor, bucket, out);
    }
}

// Round 11
// 138.538 us; speedup vs baseline: 1.0848x; 1.0848x over previous
//
#include <hip/hip_runtime.h>

#define N_NODES  50000
#define N_EDGES  600000
#define CHANNELS 128
#define HEADS    8
#define HEAD_DIM 16     // CHANNELS / HEADS
#define CAP      64     // bucket capacity; degrees ~ Poisson(12), P(deg>64) ~ 0

#define NBINS    256    // dst bins; bin = dst*NBINS/N_NODES (~196 nodes/bin)
#define CHUNK_E  1024   // edges per chunk
#define NCHUNK   ((N_EDGES + CHUNK_E - 1) / CHUNK_E)     // 586
#define SEGCAP   2816   // per-bin edge segment capacity (mean 2344, +~10 sigma)
#define NPB      200    // max nodes per bin (196) rounded up

#define LOGIT_VB ((N_NODES * (CHANNELS / 4)) / 256)      // 6250
#define WPB      4      // waves (nodes) per block in the fused kernel

// ---------------------------------------------------------------------------
// A: per-chunk LDS histogram over dst bins (no global atomics), plus the
//    per-node logit halves + bf16(x) sweep folded in as extra blocks.
// ---------------------------------------------------------------------------
__global__ void hist_logit_kernel(const float* __restrict__ x,
                                  const float* __restrict__ att,
                                  const int*   __restrict__ dst,
                                  int*            __restrict__ hist,
                                  float*          __restrict__ ls8,
                                  float*          __restrict__ ld8,
                                  unsigned short* __restrict__ xb) {
    int b = blockIdx.x;
    int t = threadIdx.x;
    if (b < NCHUNK) {
        __shared__ int lh[NBINS];
        lh[t] = 0;
        __syncthreads();
        int base = b * CHUNK_E;
#pragma unroll
        for (int k = 0; k < 4; ++k) {
            int e = base + t + k * 256;
            if (e < N_EDGES) {
                unsigned bin = (unsigned)(dst[e] * NBINS) / N_NODES;
                atomicAdd(&lh[bin], 1);          // LDS atomic
            }
        }
        __syncthreads();
        hist[b * NBINS + t] = lh[t];
    } else {
        int gid = (b - NCHUNK) * 256 + t;        // (node, float4-slot)
        int n  = gid >> 5;                       // 32 float4s per node
        int c4 = gid & 31;
        int h  = c4 >> 2;
        int j4 = c4 & 3;

        float4 v = ((const float4*)x)[gid];

        // bf16 round-to-nearest-even, packed 8B store
        unsigned int ux = __float_as_uint(v.x), uy = __float_as_uint(v.y);
        unsigned int uz = __float_as_uint(v.z), uw = __float_as_uint(v.w);
        ushort4 pk;
        pk.x = (unsigned short)((ux + 0x7FFFu + ((ux >> 16) & 1u)) >> 16);
        pk.y = (unsigned short)((uy + 0x7FFFu + ((uy >> 16) & 1u)) >> 16);
        pk.z = (unsigned short)((uz + 0x7FFFu + ((uz >> 16) & 1u)) >> 16);
        pk.w = (unsigned short)((uw + 0x7FFFu + ((uw >> 16) & 1u)) >> 16);
        ((ushort4*)xb)[gid] = pk;

        float4 as4 = ((const float4*)att)[h * 8 + j4];
        float4 ad4 = ((const float4*)att)[h * 8 + 4 + j4];
        float ts = v.x * as4.x + v.y * as4.y + v.z * as4.z + v.w * as4.w;
        float td = v.x * ad4.x + v.y * ad4.y + v.z * ad4.z + v.w * ad4.w;
        ts += __shfl_xor(ts, 1, 4); ts += __shfl_xor(ts, 2, 4);
        td += __shfl_xor(td, 1, 4); td += __shfl_xor(td, 2, 4);
        if (j4 == 0) {
            ls8[n * HEADS + h] = ts;
            ld8[n * HEADS + h] = td;
        }
    }
}

// ---------------------------------------------------------------------------
// B: per-bin exclusive scan over chunks: offm[chunk][bin], bincnt[bin].
// One block per bin, 1024-thread LDS Hillis-Steele (NCHUNK=586 <= 1024).
// ---------------------------------------------------------------------------
__global__ void scan_kernel(const int* __restrict__ hist,
                            int* __restrict__ offm,
                            int* __restrict__ bincnt) {
    __shared__ int lds[1024];
    int bin = blockIdx.x;
    int t = threadIdx.x;
    int v = (t < NCHUNK) ? hist[t * NBINS + bin] : 0;
    lds[t] = v;
    __syncthreads();
    for (int off = 1; off < 1024; off <<= 1) {
        int u = (t >= off) ? lds[t - off] : 0;
        __syncthreads();
        lds[t] += u;
        __syncthreads();
    }
    if (t < NCHUNK) offm[t * NBINS + bin] = lds[t] - v;   // exclusive
    if (t == 1023) bincnt[bin] = lds[t];                  // bin total
}

// ---------------------------------------------------------------------------
// C: deterministic scatter of packed (src,dst) into per-bin segments.
// Rank within (chunk,bin) via LDS atomic; global slot = offm + rank.
// Scattered 4B writes confined to ~11KB L2-resident segments.
// ---------------------------------------------------------------------------
__global__ void binscatter_kernel(const int* __restrict__ src,
                                  const int* __restrict__ dst,
                                  const int* __restrict__ offm,
                                  unsigned*  __restrict__ ebuf) {
    __shared__ int loff[NBINS];
    __shared__ int lcnt[NBINS];
    int b = blockIdx.x;
    int t = threadIdx.x;
    loff[t] = offm[b * NBINS + t];
    lcnt[t] = 0;
    __syncthreads();
    int base = b * CHUNK_E;
#pragma unroll
    for (int k = 0; k < 4; ++k) {
        int e = base + t + k * 256;
        if (e < N_EDGES) {
            int d = dst[e];
            int s = src[e];
            unsigned bin = (unsigned)(d * NBINS) / N_NODES;
            int r = atomicAdd(&lcnt[bin], 1) + loff[bin];   // LDS atomic
            if (r < SEGCAP)
                ebuf[(size_t)bin * SEGCAP + r] = (unsigned)s | ((unsigned)d << 16);
        }
    }
}

// ---------------------------------------------------------------------------
// D: one block per bin — coalesced read of the bin's edge segment, LDS-atomic
// rank into per-node counters, dense bucket + cursor write.  No global atomics.
// ---------------------------------------------------------------------------
__global__ void bucket_kernel(const unsigned* __restrict__ ebuf,
                              const int*      __restrict__ bincnt,
                              int*            __restrict__ cursor,
                              unsigned short* __restrict__ bucket) {
    __shared__ int lcnt[NPB];
    int b = blockIdx.x;
    int t = threadIdx.x;
    int n0 = (b * N_NODES + NBINS - 1) / NBINS;
    int n1 = ((b + 1) * N_NODES + NBINS - 1) / NBINS;
    int nn = n1 - n0;
    if (t < NPB) lcnt[t] = 0;
    __syncthreads();
    int cnt = min(bincnt[b], SEGCAP);
    for (int i = t; i < cnt; i += 256) {
        unsigned rec = ebuf[(size_t)b * SEGCAP + i];
        int s = (int)(rec & 0xFFFFu);
        int d = (int)(rec >> 16);
        int pos = atomicAdd(&lcnt[d - n0], 1);              // LDS atomic
        if (pos < CAP) bucket[(size_t)d * CAP + pos] = (unsigned short)s;
    }
    __syncthreads();
    if (t < nn) cursor[n0 + t] = lcnt[t];
}

// ---------------------------------------------------------------------------
// Fused GAT aggregation (R9 body; dense cursor/bucket).  One wave per node.
// Pass 1 (h=lane>>3, j=lane&7): logits in registers, 8-lane shuffle max
//   (clamped at 0 == reference's max(seg_max,0)), one exp per (edge,head)
//   -> LDS, denominator reduced in-register.
// Pass 2 (r=lane>>5, l32=lane&31): two edges per wave-load (ushort4/lane,
//   half-wave = one 256B bf16 row), window 8 slots = 16 edges in flight.
// ---------------------------------------------------------------------------
__global__ void fused_gat_kernel(const unsigned short* __restrict__ xb,
                                 const float* __restrict__ ls8,
                                 const float* __restrict__ ld8,
                                 const int*   __restrict__ cursor,
                                 const unsigned short* __restrict__ bucket,
                                 float*       __restrict__ out) {
    __shared__ float s_p[WPB * CAP * HEADS];     // 8 KB: staged softmax numerators

    int wave = threadIdx.x >> 6;
    int lane = threadIdx.x & 63;
    int n = blockIdx.x * WPB + wave;
    if (n >= N_NODES) return;
    int h = lane >> 3;                           // pass-1 head
    int j = lane & 7;
    int r   = lane >> 5;                         // pass-2: which edge of pair
    int l32 = lane & 31;                         // pass-2: channel quad
    int h2  = l32 >> 2;                          // pass-2 head

    int   cnt_raw = cursor[n];
    int   myidx   = (int)bucket[(size_t)n * CAP + lane];
    float ldst    = ld8[n * HEADS + h];
    int cnt = (cnt_raw > CAP) ? CAP : cnt_raw;

    float* sp = s_p + wave * (CAP * HEADS);

    // ---- pass 1: logits in registers, per-head max, single exp per value ----
    float av[8];
    float mymax = -1e30f;
#pragma unroll
    for (int k = 0; k < 8; ++k) {
        int i = j + 8 * k;
        av[k] = -1e30f;
        if (i < cnt) {
            int   s  = __shfl(myidx, i);
            float lg = ls8[s * HEADS + h] + ldst;
            float a  = (lg >= 0.0f) ? lg : 0.2f * lg;   // LeakyReLU(0.2)
            av[k] = a;
            mymax = fmaxf(mymax, a);
        }
    }
#pragma unroll
    for (int o = 4; o >= 1; o >>= 1) mymax = fmaxf(mymax, __shfl_xor(mymax, o, 8));
    float m = fmaxf(mymax, 0.0f);                // reference clamps seg_max at 0

    float myl = 0.0f;
#pragma unroll
    for (int k = 0; k < 8; ++k) {
        int i = j + 8 * k;
        if (i < cnt) {
            float p = __expf(av[k] - m);
            sp[i * HEADS + h] = p;               // 2-way bank aliasing only
            myl += p;
        }
    }
#pragma unroll
    for (int o = 4; o >= 1; o >>= 1) myl += __shfl_xor(myl, o, 8);

    // ---- pass 2: weighted accumulate, 2 edges/load, window 8 slots ----
#define LP(k) ( ((const uint2*)(xb + (size_t)__shfl(myidx, ((2*(k)+r) < cnt) ? (2*(k)+r) : 0) * CHANNELS))[l32] )
    uint2 q[8];
#pragma unroll
    for (int k = 0; k < 8; ++k) q[k] = LP(k);

    float a0 = 0.f, a1 = 0.f, a2 = 0.f, a3 = 0.f;
    int npair = (cnt + 1) >> 1;
    int k = 0;
    for (; k + 4 <= npair; k += 4) {
#pragma unroll
        for (int u = 0; u < 4; ++u) {
            int e2 = 2 * (k + u) + r;
            float p = (e2 < cnt) ? sp[e2 * HEADS + h2] : 0.0f;
            uint2 qq = q[u];
            a0 += p * __uint_as_float(qq.x << 16);
            a1 += p * __uint_as_float(qq.x & 0xFFFF0000u);
            a2 += p * __uint_as_float(qq.y << 16);
            a3 += p * __uint_as_float(qq.y & 0xFFFF0000u);
        }
#pragma unroll
        for (int u = 0; u < 4; ++u) q[u] = q[u + 4];
#pragma unroll
        for (int u = 0; u < 4; ++u) q[u + 4] = LP(k + 8 + u);
    }
    for (; k < npair; ++k) {                     // tail 0..3 pairs
        int e2 = 2 * k + r;
        float p = (e2 < cnt) ? sp[e2 * HEADS + h2] : 0.0f;
        uint2 qq = q[0];
        a0 += p * __uint_as_float(qq.x << 16);
        a1 += p * __uint_as_float(qq.x & 0xFFFF0000u);
        a2 += p * __uint_as_float(qq.y << 16);
        a3 += p * __uint_as_float(qq.y & 0xFFFF0000u);
#pragma unroll
        for (int u = 0; u < 7; ++u) q[u] = q[u + 1];
    }
#undef LP

    a0 += __shfl_xor(a0, 32);
    a1 += __shfl_xor(a1, 32);
    a2 += __shfl_xor(a2, 32);
    a3 += __shfl_xor(a3, 32);

    float denom = __shfl(myl, h2 * 8);
    float inv = 1.0f / fmaxf(denom, 1e-10f);

    if (lane < 32) {
        float4 o4 = make_float4(a0 * inv, a1 * inv, a2 * inv, a3 * inv);
        ((float4*)(out + (size_t)n * CHANNELS))[l32] = o4;
    }
}

// ---------------------------------------------------------------------------
extern "C" void kernel_launch(void* const* d_in, const int* in_sizes, int n_in,
                              void* d_out, int out_size, void* d_ws, size_t ws_size,
                              hipStream_t stream) {
    const float* x   = (const float*)d_in[0];
    const int*   ei  = (const int*)  d_in[1];   // (2, N_EDGES) row-major
    const float* att = (const float*)d_in[2];
    const int* src = ei;
    const int* dst = ei + N_EDGES;
    float* out = (float*)d_out;

    // Workspace layout (no memsets needed — every read location written first):
    //   hist   : NCHUNK*NBINS ints           (0.6 MB)
    //   offm   : NCHUNK*NBINS ints           (0.6 MB)
    //   bincnt : NBINS ints
    //   ebuf   : NBINS*SEGCAP uints          (2.9 MB)
    //   cursor : N_NODES ints                (0.2 MB)
    //   bucket : N_NODES*CAP ushorts         (6.4 MB)
    //   ls8    : N_NODES*HEADS floats        (1.6 MB)
    //   ld8    : N_NODES*HEADS floats        (1.6 MB)
    //   xb     : N_NODES*CHANNELS ushorts    (12.8 MB)
    int*            hist   = (int*)d_ws;
    int*            offm   = hist + (size_t)NCHUNK * NBINS;
    int*            bincnt = offm + (size_t)NCHUNK * NBINS;
    unsigned*       ebuf   = (unsigned*)(bincnt + NBINS);
    int*            cursor = (int*)(ebuf + (size_t)NBINS * SEGCAP);
    unsigned short* bucket = (unsigned short*)(cursor + N_NODES);
    float*          ls8    = (float*)(bucket + (size_t)N_NODES * CAP);
    float*          ld8    = ls8 + (size_t)N_NODES * HEADS;
    unsigned short* xb     = (unsigned short*)(ld8 + (size_t)N_NODES * HEADS);

    hist_logit_kernel<<<NCHUNK + LOGIT_VB, 256, 0, stream>>>(
        x, att, dst, hist, ls8, ld8, xb);
    scan_kernel<<<NBINS, 1024, 0, stream>>>(hist, offm, bincnt);
    binscatter_kernel<<<NCHUNK, 256, 0, stream>>>(src, dst, offm, ebuf);
    bucket_kernel<<<NBINS, 256, 0, stream>>>(ebuf, bincnt, cursor, bucket);
    fused_gat_kernel<<<(N_NODES + WPB - 1) / WPB, 64 * WPB, 0, stream>>>(
        xb, ls8, ld8, cursor, bucket, out);
}